// Round 10
// baseline (747.056 us; speedup 1.0000x reference)
//
#include <hip/hip_runtime.h>

// HypergraphGuidedChebNet on MI355X.
//   1. k_hist (HB=64): per-block LDS histograms (packed 16-bit) + rank capture
//   2. k_combine  3. scan_blk  4. scan_add (top-scan fused)  5. fill CSR
//   6. k_normsinit (norms + V0/acc init fused)
//   7. 10x [phaseA (2 slabs, 2 edges/wave, 4 streams x 8 lanes),
//           phaseB (2 slab-tasks/node)]
//   8. bf16 MFMA GEMM
//
// Round 17: r9 was neutral (735 vs 727): HB=128 doubled hist writeback +
//   combine loop, cancelling occupancy gain -> HB back to 64; keep the two
//   dispatch fusions (sound, passed). Main change: phaseA stream geometry.
//   r8's slab split forced 8 streams x 8 lanes -> stream length deg/8~10,
//   unroll-4 engaged ~once (r4's short-stream lesson, milder). Now 2 edges
//   per wave: each 32-lane half = one edge-slab, 4 streams x 8 lanes
//   (length ~20, 5 unroll iters — the proven r3 loop shape), reduction
//   2 stages (xor8,16) not 3. Same 32 gathers in flight per wave.

#define N_NODES 50000
#define N_EDGES 10000
#define NNZ     800000
#define F_IN    128
#define HID     512
#define R16     16           // 16 uint4 per bf16 row
#define NB_E    10           // scan blocks, edges
#define NB_N    49           // scan blocks, nodes
#define HB      64           // histogram blocks
#define NW_E    (N_EDGES / 2)
#define NW_N    (N_NODES / 2)

typedef __attribute__((ext_vector_type(8))) short bf16x8;
typedef __attribute__((ext_vector_type(4))) float f32x4;

static __device__ __forceinline__ unsigned short f2bf(float f) {
    union { float f; unsigned u; } c; c.f = f;
    unsigned u = c.u;
    unsigned r = (u + 0x7fffu + ((u >> 16) & 1u)) >> 16;
    return (unsigned short)r;
}
static __device__ __forceinline__ float blo(unsigned u) {
    union { unsigned u; float f; } c; c.u = u << 16; return c.f;
}
static __device__ __forceinline__ float bhi(unsigned u) {
    union { unsigned u; float f; } c; c.u = u & 0xffff0000u; return c.f;
}
static __device__ __forceinline__ unsigned pack2(float lo, float hi) {
    return (unsigned)f2bf(lo) | ((unsigned)f2bf(hi) << 16);
}

// ---------------------------------------------------------------- LDS histogram + ranks
// HB=64 blocks x 1024 threads, grid-stride (stride 65536).
// Per-block element count <= 13312 < 65536: no carry into high half.
__global__ __launch_bounds__(1024) void k_hist(const int* __restrict__ hidx,
                                               unsigned short* __restrict__ loc_e,
                                               unsigned short* __restrict__ loc_v,
                                               unsigned* __restrict__ hist_e,
                                               unsigned* __restrict__ hist_n) {
    __shared__ unsigned she[NW_E];
    __shared__ unsigned shn[NW_N];
    int tid = (int)threadIdx.x;
    for (int w = tid; w < NW_E; w += 1024) she[w] = 0;
    for (int w = tid; w < NW_N; w += 1024) shn[w] = 0;
    __syncthreads();
    int bid = (int)blockIdx.x;
    for (int i = bid * 1024 + tid; i < NNZ; i += HB * 1024) {
        int v = hidx[i];
        int e = hidx[NNZ + i];
        v = min(max(v, 0), N_NODES - 1);
        e = min(max(e, 0), N_EDGES - 1);
        int se = (e & 1) * 16;
        int sv = (v & 1) * 16;
        unsigned oe = atomicAdd(&she[e >> 1], 1u << se);
        unsigned ov = atomicAdd(&shn[v >> 1], 1u << sv);
        loc_e[i] = (unsigned short)((oe >> se) & 0xFFFFu);
        loc_v[i] = (unsigned short)((ov >> sv) & 0xFFFFu);
    }
    __syncthreads();
    for (int w = tid; w < NW_E; w += 1024) hist_e[bid * NW_E + w] = she[w];
    for (int w = tid; w < NW_N; w += 1024) hist_n[bid * NW_N + w] = shn[w];
}

// ---------------------------------------------------------------- replica combine
__global__ void k_combine(const unsigned* __restrict__ hist_e,
                          const unsigned* __restrict__ hist_n,
                          int* __restrict__ base_e,
                          int* __restrict__ base_n,
                          int* __restrict__ counts_e,
                          int* __restrict__ counts_n) {
    int i = blockIdx.x * blockDim.x + threadIdx.x;
    if (i < N_EDGES) {
        int sh = (i & 1) * 16;
        int w = i >> 1;
        int s = 0;
#pragma unroll 8
        for (int b = 0; b < HB; ++b) {
            base_e[b * N_EDGES + i] = s;
            s += (int)((hist_e[b * NW_E + w] >> sh) & 0xFFFFu);
        }
        counts_e[i] = s;
    }
    if (i < N_NODES) {
        int sh = (i & 1) * 16;
        int w = i >> 1;
        int s = 0;
#pragma unroll 8
        for (int b = 0; b < HB; ++b) {
            base_n[b * N_NODES + i] = s;
            s += (int)((hist_n[b * NW_N + w] >> sh) & 0xFFFFu);
        }
        counts_n[i] = s;
    }
}

// ---------------------------------------------------------------- fused scan p1 (edges+nodes)
__global__ __launch_bounds__(1024) void k_scan_blk2(const int* __restrict__ ce,
                                                    const int* __restrict__ cn,
                                                    int* __restrict__ oute,
                                                    int* __restrict__ outn,
                                                    int* __restrict__ pe,
                                                    int* __restrict__ pn) {
    __shared__ int sd[1024];
    int b = (int)blockIdx.x;
    const int* counts; int n; int* out; int* partial; int lb;
    if (b < NB_E) { counts = ce; n = N_EDGES; out = oute; partial = pe; lb = b; }
    else          { counts = cn; n = N_NODES; out = outn; partial = pn; lb = b - NB_E; }
    int tid = (int)threadIdx.x;
    int i = lb * 1024 + tid;
    int v = (i < n) ? counts[i] : 0;
    sd[tid] = v;
    __syncthreads();
    for (int off = 1; off < 1024; off <<= 1) {
        int t = (tid >= off) ? sd[tid - off] : 0;
        __syncthreads();
        sd[tid] += t;
        __syncthreads();
    }
    if (i < n) out[i] = sd[tid] - v;
    if (tid == 1023) partial[lb] = sd[1023];
}

// ---------------------------------------------------------------- scan p2 (top fused in)
// partial[] holds RAW per-chunk sums. Each block reduces partial[0..lb) for
// its own offset; the last chunk's block also writes the grand total out[n].
__global__ __launch_bounds__(1024) void k_scan_add2(int* __restrict__ oute,
                                                    int* __restrict__ outn,
                                                    const int* __restrict__ pe,
                                                    const int* __restrict__ pn) {
    __shared__ int s_add;
    int b = (int)blockIdx.x;
    int* out; const int* partial; int n; int lb; int nbl;
    if (b < NB_E) { out = oute; partial = pe; n = N_EDGES; lb = b; nbl = NB_E; }
    else          { out = outn; partial = pn; n = N_NODES; lb = b - NB_E; nbl = NB_N; }
    int tid = (int)threadIdx.x;
    if (tid < 64) {
        int v = (tid < lb) ? partial[tid] : 0;
        for (int off = 1; off < 64; off <<= 1) v += __shfl_xor(v, off);
        if (tid == 0) {
            s_add = v;                                   // = sum partial[0..lb)
            if (lb == nbl - 1) out[n] = v + partial[lb]; // grand total
        }
    }
    __syncthreads();
    int add = s_add;
    int i = lb * 1024 + tid;
    if (i < n) out[i] += add;
}

// ---------------------------------------------------------------- CSR fill (atomic-free)
// Element i was processed by hist block wg = (i>>10) & (HB-1).
__global__ void k_fill(const int* __restrict__ hidx,
                       const int* __restrict__ edge_ptr,
                       const int* __restrict__ node_ptr,
                       const unsigned short* __restrict__ loc_e,
                       const unsigned short* __restrict__ loc_v,
                       const int* __restrict__ base_e,
                       const int* __restrict__ base_n,
                       int* __restrict__ edge_node,
                       int* __restrict__ node_edge) {
    int i = blockIdx.x * blockDim.x + threadIdx.x;
    if (i >= NNZ) return;
    int wg = (i >> 10) & (HB - 1);
    int v = hidx[i];
    int e = hidx[NNZ + i];
    v = min(max(v, 0), N_NODES - 1);
    e = min(max(e, 0), N_EDGES - 1);
    edge_node[edge_ptr[e] + base_e[wg * N_EDGES + e] + (int)loc_e[i]] = v;
    node_edge[node_ptr[v] + base_n[wg * N_NODES + v] + (int)loc_v[i]] = e;
}

// ---------------------------------------------------------------- norms + init fused
__global__ void k_normsinit(const float* __restrict__ ew,
                            const int* __restrict__ edge_ptr,
                            const int* __restrict__ node_ptr,
                            const int* __restrict__ node_edge,
                            const float* __restrict__ x,
                            const float* __restrict__ theta,
                            float* __restrict__ dv_is,
                            float* __restrict__ de_w,
                            uint4* __restrict__ bufA,
                            float* __restrict__ acc) {
    __shared__ float sh_w[256];
    int tid = (int)threadIdx.x;
    int gi = (int)blockIdx.x * 256 + tid;
    if (gi < N_NODES) {
        int s = node_ptr[gi], t = node_ptr[gi + 1];
        float d = 0.f;
        for (int j = s; j < t; ++j) d += ew[node_edge[j]];
        float dv = (d > 0.f) ? rsqrtf(fmaxf(d, 1e-12f)) : 0.f;
        dv_is[gi] = dv;
        sh_w[tid] = (dv > 0.f) ? dv : 1.f;
    }
    if (gi < N_EDGES) {
        int c = edge_ptr[gi + 1] - edge_ptr[gi];
        de_w[gi] = ew[gi] * ((c > 0) ? (1.f / (float)c) : 0.f);
    }
    __syncthreads();
    float t0 = theta[0];
    int vbase = (int)blockIdx.x * 256;
    for (int r = tid; r < 256 * R16; r += 256) {
        int vl = r >> 4;
        int v = vbase + vl;
        if (v >= N_NODES) break;      // v ascends with r for fixed tid
        int lane = r & 15;
        int i = v * R16 + lane;
        float w = sh_w[vl];
        float4 x0 = ((const float4*)x)[2 * i];
        float4 x1 = ((const float4*)x)[2 * i + 1];
        uint4 q;
        q.x = pack2(w * x0.x, w * x0.y); q.y = pack2(w * x0.z, w * x0.w);
        q.z = pack2(w * x1.x, w * x1.y); q.w = pack2(w * x1.z, w * x1.w);
        bufA[i] = q;
        float4 a0, a1;
        a0.x = t0 * x0.x; a0.y = t0 * x0.y; a0.z = t0 * x0.z; a0.w = t0 * x0.w;
        a1.x = t0 * x1.x; a1.y = t0 * x1.y; a1.z = t0 * x1.z; a1.w = t0 * x1.w;
        ((float4*)acc)[2 * i]     = a0;
        ((float4*)acc)[2 * i + 1] = a1;
    }
}

// ---------------------------------------------------------------- phase A
// 2 slabs x 1250 blocks; 8 edges/block = 4 waves x 2 edges. Each 32-lane
// half owns one edge-slab: 4 member-streams x 8 lanes x 16B (128B row-slab
// per member). Stream length ~deg/4=20 -> unroll-4 engages ~5x. Reduction:
// xor 8, xor 16 (stays within the 32-lane half). 32 gathers in flight/wave.
__global__ void k_phaseA(const uint4* __restrict__ tin,
                         const float* __restrict__ de_w,
                         const int* __restrict__ edge_ptr,
                         const int* __restrict__ edge_node,
                         uint4* __restrict__ m_e) {
    int tid    = (int)threadIdx.x;
    int wv     = tid >> 6;
    int l64    = tid & 63;
    int half   = l64 >> 5;            // edge within wave
    int l32    = l64 & 31;
    int stream = l32 >> 3;            // 0..3
    int sl     = l32 & 7;             // uint4 col within slab
    int b      = (int)blockIdx.x;
    int slab   = (b >= (N_EDGES / 8)) ? 1 : 0;
    int e      = (b - slab * (N_EDGES / 8)) * 8 + wv * 2 + half;
    int col    = slab * 8 + sl;
    int s = edge_ptr[e], t = edge_ptr[e + 1];
    float a0=0.f,a1=0.f,a2=0.f,a3=0.f,a4=0.f,a5=0.f,a6=0.f,a7=0.f;
    int j = s + stream;
    for (; j + 12 < t; j += 16) {     // unroll-4 per stream (stride-4 members)
        int v0 = edge_node[j];
        int v1 = edge_node[j + 4];
        int v2 = edge_node[j + 8];
        int v3 = edge_node[j + 12];
        uint4 q0 = tin[v0 * R16 + col];
        uint4 q1 = tin[v1 * R16 + col];
        uint4 q2 = tin[v2 * R16 + col];
        uint4 q3 = tin[v3 * R16 + col];
        a0 += (blo(q0.x) + blo(q1.x)) + (blo(q2.x) + blo(q3.x));
        a1 += (bhi(q0.x) + bhi(q1.x)) + (bhi(q2.x) + bhi(q3.x));
        a2 += (blo(q0.y) + blo(q1.y)) + (blo(q2.y) + blo(q3.y));
        a3 += (bhi(q0.y) + bhi(q1.y)) + (bhi(q2.y) + bhi(q3.y));
        a4 += (blo(q0.z) + blo(q1.z)) + (blo(q2.z) + blo(q3.z));
        a5 += (bhi(q0.z) + bhi(q1.z)) + (bhi(q2.z) + bhi(q3.z));
        a6 += (blo(q0.w) + blo(q1.w)) + (blo(q2.w) + blo(q3.w));
        a7 += (bhi(q0.w) + bhi(q1.w)) + (bhi(q2.w) + bhi(q3.w));
    }
    for (; j < t; j += 4) {
        int v0 = edge_node[j];
        uint4 q0 = tin[v0 * R16 + col];
        a0 += blo(q0.x); a1 += bhi(q0.x);
        a2 += blo(q0.y); a3 += bhi(q0.y);
        a4 += blo(q0.z); a5 += bhi(q0.z);
        a6 += blo(q0.w); a7 += bhi(q0.w);
    }
    // combine 4 streams within the 32-lane half: xor 8, xor 16
    a0 += __shfl_xor(a0, 8);  a1 += __shfl_xor(a1, 8);
    a2 += __shfl_xor(a2, 8);  a3 += __shfl_xor(a3, 8);
    a4 += __shfl_xor(a4, 8);  a5 += __shfl_xor(a5, 8);
    a6 += __shfl_xor(a6, 8);  a7 += __shfl_xor(a7, 8);
    a0 += __shfl_xor(a0, 16); a1 += __shfl_xor(a1, 16);
    a2 += __shfl_xor(a2, 16); a3 += __shfl_xor(a3, 16);
    a4 += __shfl_xor(a4, 16); a5 += __shfl_xor(a5, 16);
    a6 += __shfl_xor(a6, 16); a7 += __shfl_xor(a7, 16);
    if (stream == 0) {
        float w = de_w[e];
        uint4 o;
        o.x = pack2(a0 * w, a1 * w); o.y = pack2(a2 * w, a3 * w);
        o.z = pack2(a4 * w, a5 * w); o.w = pack2(a6 * w, a7 * w);
        m_e[e * R16 + col] = o;
    }
}

// ---------------------------------------------------------------- phase B (2 slab-tasks/node)
// Blocks [0,3125): slab 0; [3125,6250): slab 1. 16 nodes/block; per node
// 16 lanes = 2 edge-streams x 8 col-lanes.
__global__ void k_phaseB(const uint4* __restrict__ m_e,
                         const uint4* __restrict__ tin,
                         const float* __restrict__ dv_is,
                         const int* __restrict__ node_ptr,
                         const int* __restrict__ node_edge,
                         uint4* __restrict__ tio,
                         float* __restrict__ acc,
                         const float* __restrict__ theta, int k,
                         float ca, float cb, int accMode) {
    int tid    = (int)threadIdx.x;
    int g      = tid >> 4;            // node slot 0..15
    int t16    = tid & 15;
    int stream = t16 >> 3;            // 0..1
    int sl     = t16 & 7;
    int b      = (int)blockIdx.x;
    int slab   = (b >= (N_NODES / 16)) ? 1 : 0;
    int v      = (b - slab * (N_NODES / 16)) * 16 + g;
    int col    = slab * 8 + sl;
    int s = node_ptr[v], t = node_ptr[v + 1];
    float s0=0.f,s1=0.f,s2=0.f,s3=0.f,s4=0.f,s5=0.f,s6=0.f,s7=0.f;
    int j = s + stream;
    for (; j + 2 < t; j += 4) {
        int e0 = node_edge[j];
        int e1 = node_edge[j + 2];
        uint4 q0 = m_e[e0 * R16 + col];
        uint4 q1 = m_e[e1 * R16 + col];
        s0 += blo(q0.x) + blo(q1.x); s1 += bhi(q0.x) + bhi(q1.x);
        s2 += blo(q0.y) + blo(q1.y); s3 += bhi(q0.y) + bhi(q1.y);
        s4 += blo(q0.z) + blo(q1.z); s5 += bhi(q0.z) + bhi(q1.z);
        s6 += blo(q0.w) + blo(q1.w); s7 += bhi(q0.w) + bhi(q1.w);
    }
    if (j < t) {
        int e0 = node_edge[j];
        uint4 q0 = m_e[e0 * R16 + col];
        s0 += blo(q0.x); s1 += bhi(q0.x);
        s2 += blo(q0.y); s3 += bhi(q0.y);
        s4 += blo(q0.z); s5 += bhi(q0.z);
        s6 += blo(q0.w); s7 += bhi(q0.w);
    }
    s0 += __shfl_xor(s0, 8); s1 += __shfl_xor(s1, 8);
    s2 += __shfl_xor(s2, 8); s3 += __shfl_xor(s3, 8);
    s4 += __shfl_xor(s4, 8); s5 += __shfl_xor(s5, 8);
    s6 += __shfl_xor(s6, 8); s7 += __shfl_xor(s7, 8);
    if (stream == 0) {
        float dvv = dv_is[v];
        float scf = ca * dvv * dvv;           // 0 for isolated nodes (sum=0 anyway)
        int idx = v * R16 + col;
        uint4 tp = tio[idx];
        float t0 = scf * s0 + cb * blo(tp.x);
        float t1 = scf * s1 + cb * bhi(tp.x);
        float t2 = scf * s2 + cb * blo(tp.y);
        float t3 = scf * s3 + cb * bhi(tp.y);
        float t4 = scf * s4 + cb * blo(tp.z);
        float t5 = scf * s5 + cb * bhi(tp.z);
        float t6 = scf * s6 + cb * blo(tp.w);
        float t7 = scf * s7 + cb * bhi(tp.w);
        uint4 tn;
        tn.x = pack2(t0, t1); tn.y = pack2(t2, t3);
        tn.z = pack2(t4, t5); tn.w = pack2(t6, t7);
        tio[idx] = tn;
        if (accMode) {
            float thk = theta[k];
            float a0 = thk * t0, a1 = thk * t1, a2 = thk * t2, a3 = thk * t3;
            float a4 = thk * t4, a5 = thk * t5, a6 = thk * t6, a7 = thk * t7;
            if (accMode >= 2) {
                float th1 = theta[k - 1];
                uint4 tq = tin[idx];          // V_{k-1}, coalesced
                a0 += th1 * blo(tq.x); a1 += th1 * bhi(tq.x);
                a2 += th1 * blo(tq.y); a3 += th1 * bhi(tq.y);
                a4 += th1 * blo(tq.z); a5 += th1 * bhi(tq.z);
                a6 += th1 * blo(tq.w); a7 += th1 * bhi(tq.w);
            }
            if (accMode >= 3) {
                float th2 = theta[k - 2];
                a0 += th2 * blo(tp.x); a1 += th2 * bhi(tp.x);
                a2 += th2 * blo(tp.y); a3 += th2 * bhi(tp.y);
                a4 += th2 * blo(tp.z); a5 += th2 * bhi(tp.z);
                a6 += th2 * blo(tp.w); a7 += th2 * bhi(tp.w);
            }
            float iw = (dvv > 0.f) ? (1.f / dvv) : 1.f;
            float4* acc4 = (float4*)acc;
            int ai = v * 32 + col * 2;
            float4 a = acc4[ai];
            a.x += iw * a0; a.y += iw * a1; a.z += iw * a2; a.w += iw * a3;
            acc4[ai] = a;
            float4 bvec = acc4[ai + 1];
            bvec.x += iw * a4; bvec.y += iw * a5; bvec.z += iw * a6; bvec.w += iw * a7;
            acc4[ai + 1] = bvec;
        }
    }
}

// ---------------------------------------------------------------- MFMA GEMM
// out = relu(A @ W^T + b), A=accv fp32 [M][128], W fp32 [512][128].
// Block: 256thr=4 waves, tile M=64 N=64, K=128 fully staged.
// LDS row = 136 shorts (272B): conflict-free. XCD swizzle: id&7 = band.
#define M_TILES 782
__global__ __launch_bounds__(256) void k_gemm(const float* __restrict__ A,
                                              const float* __restrict__ W,
                                              const float* __restrict__ bias,
                                              float* __restrict__ out) {
    __shared__ short Asm[64 * 136];
    __shared__ short Wsm[64 * 136];
    int id  = (int)blockIdx.x;
    int xcd = id & 7;
    int sub = id >> 3;
    int h_t = sub & 7;
    int m_i = sub >> 3;                 // 0..97
    int m_t = xcd * 98 + m_i;
    if (m_t >= M_TILES) return;
    int m0 = m_t * 64;
    int h0 = h_t * 64;
    int tid = (int)threadIdx.x;

    const float4* A4 = (const float4*)A;
    const float4* W4 = (const float4*)W;
#pragma unroll
    for (int i = 0; i < 4; ++i) {
        int c   = tid + i * 256;        // 0..1023
        int row = c >> 4;               // 0..63
        int q4  = c & 15;               // uint4 column
        int gr = m0 + row;
        float4 a0, a1;
        if (gr < N_NODES) {
            a0 = A4[(size_t)gr * 32 + q4 * 2];
            a1 = A4[(size_t)gr * 32 + q4 * 2 + 1];
        } else {
            a0 = make_float4(0.f, 0.f, 0.f, 0.f);
            a1 = a0;
        }
        uint4 pa;
        pa.x = pack2(a0.x, a0.y); pa.y = pack2(a0.z, a0.w);
        pa.z = pack2(a1.x, a1.y); pa.w = pack2(a1.z, a1.w);
        *(uint4*)&Asm[row * 136 + q4 * 8] = pa;
        float4 w0 = W4[(size_t)(h0 + row) * 32 + q4 * 2];
        float4 w1 = W4[(size_t)(h0 + row) * 32 + q4 * 2 + 1];
        uint4 pw;
        pw.x = pack2(w0.x, w0.y); pw.y = pack2(w0.z, w0.w);
        pw.z = pack2(w1.x, w1.y); pw.w = pack2(w1.z, w1.w);
        *(uint4*)&Wsm[row * 136 + q4 * 8] = pw;
    }
    __syncthreads();

    int lane = tid & 63;
    int wv   = tid >> 6;                // wave 0..3 -> m rows wv*16..+15
    int l16  = lane & 15;
    int quad = lane >> 4;

    f32x4 acc[4];
#pragma unroll
    for (int n = 0; n < 4; ++n) acc[n] = (f32x4){0.f, 0.f, 0.f, 0.f};

#pragma unroll
    for (int ks = 0; ks < 4; ++ks) {
        int k0 = ks * 32;
        bf16x8 af = *(const bf16x8*)&Asm[(wv * 16 + l16) * 136 + k0 + quad * 8];
#pragma unroll
        for (int n = 0; n < 4; ++n) {
            bf16x8 bf = *(const bf16x8*)&Wsm[(n * 16 + l16) * 136 + k0 + quad * 8];
            acc[n] = __builtin_amdgcn_mfma_f32_16x16x32_bf16(af, bf, acc[n], 0, 0, 0);
        }
    }

    // C/D layout: col = lane&15, row = quad*4 + reg   (m89/m91-verified)
#pragma unroll
    for (int n = 0; n < 4; ++n) {
        float bb = bias[h0 + n * 16 + l16];
#pragma unroll
        for (int r = 0; r < 4; ++r) {
            int gr = m0 + wv * 16 + quad * 4 + r;
            if (gr < N_NODES)
                out[(size_t)gr * HID + h0 + n * 16 + l16] =
                    fmaxf(acc[n][r] + bb, 0.f);
        }
    }
}

// ----------------------------------------------------------------
extern "C" void kernel_launch(void* const* d_in, const int* in_sizes, int n_in,
                              void* d_out, int out_size, void* d_ws, size_t ws_size,
                              hipStream_t stream) {
    const float* x     = (const float*)d_in[0];
    const int*   hidx  = (const int*)d_in[1];    // int32, [2, NNZ] row-major
    const float* ew    = (const float*)d_in[2];
    const float* theta = (const float*)d_in[3];
    const float* w1    = (const float*)d_in[4];
    const float* b1    = (const float*)d_in[5];
    float*       out   = (float*)d_out;
    int kp1 = in_sizes[3];  // K+1 (= 11)
    int K   = kp1 - 1;

    // ---- scratch carved out of d_out (all dead before k_gemm's writes) ----
    char* ob = (char*)d_out;
    size_t oo = 0;
    auto oalloc = [&](size_t bytes) -> void* {
        void* p = ob + oo;
        oo = (oo + bytes + 255) & ~(size_t)255;
        return p;
    };
    uint4* bufA      = (uint4*)oalloc((size_t)N_NODES * F_IN * 2);
    uint4* bufB      = (uint4*)oalloc((size_t)N_NODES * F_IN * 2);
    uint4* m_e       = (uint4*)oalloc((size_t)N_EDGES * F_IN * 2);
    int*   edge_node = (int*)oalloc((size_t)NNZ * 4);
    int*   node_edge = (int*)oalloc((size_t)NNZ * 4);
    unsigned short* loc_e = (unsigned short*)oalloc((size_t)NNZ * 2);
    unsigned short* loc_v = (unsigned short*)oalloc((size_t)NNZ * 2);
    unsigned* hist_e = (unsigned*)oalloc((size_t)HB * NW_E * 4);
    unsigned* hist_n = (unsigned*)oalloc((size_t)HB * NW_N * 4);
    int*   base_e    = (int*)oalloc((size_t)HB * N_EDGES * 4);
    int*   base_n    = (int*)oalloc((size_t)HB * N_NODES * 4);
    int*   counts_e  = (int*)oalloc((size_t)N_EDGES * 4);
    int*   counts_n  = (int*)oalloc((size_t)N_NODES * 4);

    // ---- d_ws (~26MB) ----
    char* ws = (char*)d_ws;
    size_t off = 0;
    auto alloc = [&](size_t bytes) -> void* {
        void* p = ws + off;
        off = (off + bytes + 255) & ~(size_t)255;
        return p;
    };
    float* accv     = (float*)alloc((size_t)N_NODES * F_IN * 4);
    float* dv_is    = (float*)alloc((size_t)N_NODES * 4);
    float* de_w     = (float*)alloc((size_t)N_EDGES * 4);
    int*   edge_ptr = (int*)alloc((size_t)(N_EDGES + 1) * 4);
    int*   node_ptr = (int*)alloc((size_t)(N_NODES + 1) * 4);
    int*   part_e   = (int*)alloc(64 * 4);
    int*   part_n   = (int*)alloc(64 * 4);

    k_hist<<<HB, 1024, 0, stream>>>(hidx, loc_e, loc_v, hist_e, hist_n);
    k_combine<<<(N_NODES + 255) / 256, 256, 0, stream>>>(hist_e, hist_n,
                                                         base_e, base_n,
                                                         counts_e, counts_n);

    k_scan_blk2<<<NB_E + NB_N, 1024, 0, stream>>>(counts_e, counts_n, edge_ptr, node_ptr,
                                                  part_e, part_n);
    k_scan_add2<<<NB_E + NB_N, 1024, 0, stream>>>(edge_ptr, node_ptr, part_e, part_n);

    k_fill<<<(NNZ + 255) / 256, 256, 0, stream>>>(hidx, edge_ptr, node_ptr,
                                                  loc_e, loc_v, base_e, base_n,
                                                  edge_node, node_edge);
    k_normsinit<<<(N_NODES + 255) / 256, 256, 0, stream>>>(ew, edge_ptr, node_ptr,
                                                           node_edge, x, theta,
                                                           dv_is, de_w, bufA, accv);

    for (int k = 1; k <= K; ++k) {
        const uint4* tin = (k & 1) ? bufA : bufB;   // V_{k-1}
        uint4*       tio = (k & 1) ? bufB : bufA;   // V_{k-2} -> V_k (in place)
        float ca = (k == 1) ? -1.f : -2.f;
        float cb = (k == 1) ? 0.f : -1.f;
        int accMode = 0;
        if (k % 3 == 0) accMode = 3;
        else if (k == K && (K % 3) != 0) accMode = K % 3;
        // 2 slabs x 1250 edge-blocks (8 edges each); 2 slabs x 3125 node-blocks
        k_phaseA<<<2 * (N_EDGES / 8), 256, 0, stream>>>(tin, de_w, edge_ptr, edge_node, m_e);
        k_phaseB<<<2 * (N_NODES / 16), 256, 0, stream>>>(m_e, tin, dv_is, node_ptr, node_edge,
                                                         tio, accv, theta, k, ca, cb, accMode);
    }

    // 8 bands x 98 m-tiles x 8 h-tiles (2 tail tiles early-return)
    k_gemm<<<8 * 98 * 8, 256, 0, stream>>>(accv, w1, b1, out);
}

// Round 11
// 727.027 us; speedup vs baseline: 1.0276x; 1.0276x over previous
//
#include <hip/hip_runtime.h>

// HypergraphGuidedChebNet on MI355X — FINAL (round-8 configuration, 727us).
//   1. k_hist: per-block LDS histograms (packed 16-bit) + local-rank capture
//   2. k_combine  3. scan_blk  4. scan_top  5. scan_add  6. fill CSR
//   7. norms2  8. init  9. 10x [phaseA (2 feature-slabs in one grid),
//      phaseB (2 slab-tasks/node)]  10. bf16 MFMA GEMM
//
// Session summary (what's proven on HW):
//   - global returning atomics: memory-side, ~25Gop/s, 32B/op writeback ->
//     replaced with LDS counting-sort (zero global atomics).
//   - phaseA gather local optimum: 16B/lane, one edge per wave, long streams
//     (deg/8), unroll-4, slab split for working-set halving. Chunking (4B or
//     16B sub-rows), 2-edge waves, HB=128: all regress or neutral.
//   - mega-kernels dead: cooperative launch fails under harness; manual
//     agent-scope barrier forces per-WG L2 wb/inv (FETCH 1GB, 5.6x).
//   - phaseB: grouped theta accumulation (3 terms per acc RMW) saves 320MB.
//   - GEMM: bf16 MFMA, 64x64 tile, cast-in-staging, XCD-banded swizzle.
// Plateau arithmetic: phases ~460us at ~7.3TB/s effective beyond-L2 random
// 128B gather; preproc ~45us; GEMM ~30us; rest = dispatch boundaries
// (proven unrecoverable). 727us is this design space's floor.

#define N_NODES 50000
#define N_EDGES 10000
#define NNZ     800000
#define F_IN    128
#define HID     512
#define R16     16           // 16 uint4 per bf16 row
#define NB_E    10           // scan blocks, edges
#define NB_N    49           // scan blocks, nodes
#define HB      64           // histogram blocks
#define NW_E    (N_EDGES / 2)
#define NW_N    (N_NODES / 2)

typedef __attribute__((ext_vector_type(8))) short bf16x8;
typedef __attribute__((ext_vector_type(4))) float f32x4;

static __device__ __forceinline__ unsigned short f2bf(float f) {
    union { float f; unsigned u; } c; c.f = f;
    unsigned u = c.u;
    unsigned r = (u + 0x7fffu + ((u >> 16) & 1u)) >> 16;
    return (unsigned short)r;
}
static __device__ __forceinline__ float blo(unsigned u) {
    union { unsigned u; float f; } c; c.u = u << 16; return c.f;
}
static __device__ __forceinline__ float bhi(unsigned u) {
    union { unsigned u; float f; } c; c.u = u & 0xffff0000u; return c.f;
}
static __device__ __forceinline__ unsigned pack2(float lo, float hi) {
    return (unsigned)f2bf(lo) | ((unsigned)f2bf(hi) << 16);
}

// ---------------------------------------------------------------- LDS histogram + ranks
__global__ __launch_bounds__(1024) void k_hist(const int* __restrict__ hidx,
                                               unsigned short* __restrict__ loc_e,
                                               unsigned short* __restrict__ loc_v,
                                               unsigned* __restrict__ hist_e,
                                               unsigned* __restrict__ hist_n) {
    __shared__ unsigned she[NW_E];
    __shared__ unsigned shn[NW_N];
    int tid = (int)threadIdx.x;
    for (int w = tid; w < NW_E; w += 1024) she[w] = 0;
    for (int w = tid; w < NW_N; w += 1024) shn[w] = 0;
    __syncthreads();
    int bid = (int)blockIdx.x;
    for (int i = bid * 1024 + tid; i < NNZ; i += HB * 1024) {
        int v = hidx[i];
        int e = hidx[NNZ + i];
        v = min(max(v, 0), N_NODES - 1);
        e = min(max(e, 0), N_EDGES - 1);
        int se = (e & 1) * 16;
        int sv = (v & 1) * 16;
        unsigned oe = atomicAdd(&she[e >> 1], 1u << se);
        unsigned ov = atomicAdd(&shn[v >> 1], 1u << sv);
        loc_e[i] = (unsigned short)((oe >> se) & 0xFFFFu);
        loc_v[i] = (unsigned short)((ov >> sv) & 0xFFFFu);
    }
    __syncthreads();
    for (int w = tid; w < NW_E; w += 1024) hist_e[bid * NW_E + w] = she[w];
    for (int w = tid; w < NW_N; w += 1024) hist_n[bid * NW_N + w] = shn[w];
}

// ---------------------------------------------------------------- replica combine
__global__ void k_combine(const unsigned* __restrict__ hist_e,
                          const unsigned* __restrict__ hist_n,
                          int* __restrict__ base_e,
                          int* __restrict__ base_n,
                          int* __restrict__ counts_e,
                          int* __restrict__ counts_n) {
    int i = blockIdx.x * blockDim.x + threadIdx.x;
    if (i < N_EDGES) {
        int sh = (i & 1) * 16;
        int w = i >> 1;
        int s = 0;
#pragma unroll 8
        for (int b = 0; b < HB; ++b) {
            base_e[b * N_EDGES + i] = s;
            s += (int)((hist_e[b * NW_E + w] >> sh) & 0xFFFFu);
        }
        counts_e[i] = s;
    }
    if (i < N_NODES) {
        int sh = (i & 1) * 16;
        int w = i >> 1;
        int s = 0;
#pragma unroll 8
        for (int b = 0; b < HB; ++b) {
            base_n[b * N_NODES + i] = s;
            s += (int)((hist_n[b * NW_N + w] >> sh) & 0xFFFFu);
        }
        counts_n[i] = s;
    }
}

// ---------------------------------------------------------------- fused scan p1 (edges+nodes)
__global__ __launch_bounds__(1024) void k_scan_blk2(const int* __restrict__ ce,
                                                    const int* __restrict__ cn,
                                                    int* __restrict__ oute,
                                                    int* __restrict__ outn,
                                                    int* __restrict__ pe,
                                                    int* __restrict__ pn) {
    __shared__ int sd[1024];
    int b = (int)blockIdx.x;
    const int* counts; int n; int* out; int* partial; int lb;
    if (b < NB_E) { counts = ce; n = N_EDGES; out = oute; partial = pe; lb = b; }
    else          { counts = cn; n = N_NODES; out = outn; partial = pn; lb = b - NB_E; }
    int tid = (int)threadIdx.x;
    int i = lb * 1024 + tid;
    int v = (i < n) ? counts[i] : 0;
    sd[tid] = v;
    __syncthreads();
    for (int off = 1; off < 1024; off <<= 1) {
        int t = (tid >= off) ? sd[tid - off] : 0;
        __syncthreads();
        sd[tid] += t;
        __syncthreads();
    }
    if (i < n) out[i] = sd[tid] - v;
    if (tid == 1023) partial[lb] = sd[1023];
}

// ---------------------------------------------------------------- fused scan p2 (2 waves)
__global__ void k_scan_top2(int* __restrict__ pe, int* __restrict__ pn,
                            int* __restrict__ tot_e, int* __restrict__ tot_n) {
    int w = (int)threadIdx.x >> 6;
    int lane = (int)threadIdx.x & 63;
    int* partial = w ? pn : pe;
    int nb       = w ? NB_N : NB_E;
    int* total   = w ? tot_n : tot_e;
    int v = (lane < nb) ? partial[lane] : 0;
    int incl = v;
    for (int off = 1; off < 64; off <<= 1) {
        int t = __shfl_up(incl, off);
        if (lane >= off) incl += t;
    }
    if (lane < nb) partial[lane] = incl - v;
    if (lane == 63) *total = incl;
}

// ---------------------------------------------------------------- fused scan p3
__global__ __launch_bounds__(1024) void k_scan_add2(int* __restrict__ oute,
                                                    int* __restrict__ outn,
                                                    const int* __restrict__ pe,
                                                    const int* __restrict__ pn) {
    int b = (int)blockIdx.x;
    int* out; const int* partial; int n; int lb;
    if (b < NB_E) { out = oute; partial = pe; n = N_EDGES; lb = b; }
    else          { out = outn; partial = pn; n = N_NODES; lb = b - NB_E; }
    int i = lb * 1024 + (int)threadIdx.x;
    if (i < n) out[i] += partial[lb];
}

// ---------------------------------------------------------------- CSR fill (atomic-free)
__global__ void k_fill(const int* __restrict__ hidx,
                       const int* __restrict__ edge_ptr,
                       const int* __restrict__ node_ptr,
                       const unsigned short* __restrict__ loc_e,
                       const unsigned short* __restrict__ loc_v,
                       const int* __restrict__ base_e,
                       const int* __restrict__ base_n,
                       int* __restrict__ edge_node,
                       int* __restrict__ node_edge) {
    int i = blockIdx.x * blockDim.x + threadIdx.x;
    if (i >= NNZ) return;
    int wg = (i >> 10) & (HB - 1);
    int v = hidx[i];
    int e = hidx[NNZ + i];
    v = min(max(v, 0), N_NODES - 1);
    e = min(max(e, 0), N_EDGES - 1);
    edge_node[edge_ptr[e] + base_e[wg * N_EDGES + e] + (int)loc_e[i]] = v;
    node_edge[node_ptr[v] + base_n[wg * N_NODES + v] + (int)loc_v[i]] = e;
}

// ---------------------------------------------------------------- norms from CSR
__global__ void k_norms2(const float* __restrict__ ew,
                         const int* __restrict__ edge_ptr,
                         const int* __restrict__ node_ptr,
                         const int* __restrict__ node_edge,
                         float* __restrict__ dv_is,
                         float* __restrict__ de_w) {
    int i = blockIdx.x * blockDim.x + threadIdx.x;
    if (i < N_NODES) {
        int s = node_ptr[i], t = node_ptr[i + 1];
        float d = 0.f;
        for (int j = s; j < t; ++j) d += ew[node_edge[j]];
        dv_is[i] = (d > 0.f) ? rsqrtf(fmaxf(d, 1e-12f)) : 0.f;
    }
    if (i < N_EDGES) {
        int c = edge_ptr[i + 1] - edge_ptr[i];
        de_w[i] = ew[i] * ((c > 0) ? (1.f / (float)c) : 0.f);
    }
}

// ---------------------------------------------------------------- init
__global__ void k_init(const float* __restrict__ x,
                       const float* __restrict__ theta,
                       const float* __restrict__ dv_is,
                       uint4* __restrict__ bufA,
                       float* __restrict__ acc) {
    int i = blockIdx.x * blockDim.x + threadIdx.x;
    if (i >= N_NODES * R16) return;
    int v = i >> 4;
    float dvv = dv_is[v];
    float w = (dvv > 0.f) ? dvv : 1.f;
    float4 x0 = ((const float4*)x)[2 * i];
    float4 x1 = ((const float4*)x)[2 * i + 1];
    uint4 q;
    q.x = pack2(w * x0.x, w * x0.y); q.y = pack2(w * x0.z, w * x0.w);
    q.z = pack2(w * x1.x, w * x1.y); q.w = pack2(w * x1.z, w * x1.w);
    bufA[i] = q;
    float t0 = theta[0];
    float4 a0, a1;
    a0.x = t0 * x0.x; a0.y = t0 * x0.y; a0.z = t0 * x0.z; a0.w = t0 * x0.w;
    a1.x = t0 * x1.x; a1.y = t0 * x1.y; a1.z = t0 * x1.z; a1.w = t0 * x1.w;
    ((float4*)acc)[2 * i]     = a0;
    ((float4*)acc)[2 * i + 1] = a1;
}

// ---------------------------------------------------------------- phase A (2 slabs, one grid)
// Blocks [0,2500): slab 0 (uint4 cols 0..7); [2500,5000): slab 1 (cols 8..15).
// Wave = 1 edge-slab: 8 member-streams x 8 lanes x 16B (one 128B row-slab per
// 8-lane group). Unroll-4 => 16KB in flight/wave.
__global__ void k_phaseA(const uint4* __restrict__ tin,
                         const float* __restrict__ de_w,
                         const int* __restrict__ edge_ptr,
                         const int* __restrict__ edge_node,
                         uint4* __restrict__ m_e) {
    int tid    = (int)threadIdx.x;
    int wv     = tid >> 6;
    int l64    = tid & 63;
    int stream = l64 >> 3;            // 0..7
    int sl     = l64 & 7;             // uint4 col within slab
    int b      = (int)blockIdx.x;
    int slab   = (b >= (N_EDGES / 4)) ? 1 : 0;
    int e      = (b - slab * (N_EDGES / 4)) * 4 + wv;
    int col    = slab * 8 + sl;
    int s = edge_ptr[e], t = edge_ptr[e + 1];
    float a0=0.f,a1=0.f,a2=0.f,a3=0.f,a4=0.f,a5=0.f,a6=0.f,a7=0.f;
    int j = s + stream;
    for (; j + 24 < t; j += 32) {     // unroll-4 per stream (stride-8 members)
        int v0 = edge_node[j];
        int v1 = edge_node[j + 8];
        int v2 = edge_node[j + 16];
        int v3 = edge_node[j + 24];
        uint4 q0 = tin[v0 * R16 + col];
        uint4 q1 = tin[v1 * R16 + col];
        uint4 q2 = tin[v2 * R16 + col];
        uint4 q3 = tin[v3 * R16 + col];
        a0 += (blo(q0.x) + blo(q1.x)) + (blo(q2.x) + blo(q3.x));
        a1 += (bhi(q0.x) + bhi(q1.x)) + (bhi(q2.x) + bhi(q3.x));
        a2 += (blo(q0.y) + blo(q1.y)) + (blo(q2.y) + blo(q3.y));
        a3 += (bhi(q0.y) + bhi(q1.y)) + (bhi(q2.y) + bhi(q3.y));
        a4 += (blo(q0.z) + blo(q1.z)) + (blo(q2.z) + blo(q3.z));
        a5 += (bhi(q0.z) + bhi(q1.z)) + (bhi(q2.z) + bhi(q3.z));
        a6 += (blo(q0.w) + blo(q1.w)) + (blo(q2.w) + blo(q3.w));
        a7 += (bhi(q0.w) + bhi(q1.w)) + (bhi(q2.w) + bhi(q3.w));
    }
    for (; j < t; j += 8) {
        int v0 = edge_node[j];
        uint4 q0 = tin[v0 * R16 + col];
        a0 += blo(q0.x); a1 += bhi(q0.x);
        a2 += blo(q0.y); a3 += bhi(q0.y);
        a4 += blo(q0.z); a5 += bhi(q0.z);
        a6 += blo(q0.w); a7 += bhi(q0.w);
    }
    // combine 8 streams: xor 8, 16, 32
    a0 += __shfl_xor(a0, 8);  a1 += __shfl_xor(a1, 8);
    a2 += __shfl_xor(a2, 8);  a3 += __shfl_xor(a3, 8);
    a4 += __shfl_xor(a4, 8);  a5 += __shfl_xor(a5, 8);
    a6 += __shfl_xor(a6, 8);  a7 += __shfl_xor(a7, 8);
    a0 += __shfl_xor(a0, 16); a1 += __shfl_xor(a1, 16);
    a2 += __shfl_xor(a2, 16); a3 += __shfl_xor(a3, 16);
    a4 += __shfl_xor(a4, 16); a5 += __shfl_xor(a5, 16);
    a6 += __shfl_xor(a6, 16); a7 += __shfl_xor(a7, 16);
    a0 += __shfl_xor(a0, 32); a1 += __shfl_xor(a1, 32);
    a2 += __shfl_xor(a2, 32); a3 += __shfl_xor(a3, 32);
    a4 += __shfl_xor(a4, 32); a5 += __shfl_xor(a5, 32);
    a6 += __shfl_xor(a6, 32); a7 += __shfl_xor(a7, 32);
    if (stream == 0) {
        float w = de_w[e];
        uint4 o;
        o.x = pack2(a0 * w, a1 * w); o.y = pack2(a2 * w, a3 * w);
        o.z = pack2(a4 * w, a5 * w); o.w = pack2(a6 * w, a7 * w);
        m_e[e * R16 + col] = o;
    }
}

// ---------------------------------------------------------------- phase B (2 slab-tasks/node)
// Blocks [0,3125): slab 0; [3125,6250): slab 1. 16 nodes/block; per node
// 16 lanes = 2 edge-streams x 8 col-lanes.
__global__ void k_phaseB(const uint4* __restrict__ m_e,
                         const uint4* __restrict__ tin,
                         const float* __restrict__ dv_is,
                         const int* __restrict__ node_ptr,
                         const int* __restrict__ node_edge,
                         uint4* __restrict__ tio,
                         float* __restrict__ acc,
                         const float* __restrict__ theta, int k,
                         float ca, float cb, int accMode) {
    int tid    = (int)threadIdx.x;
    int g      = tid >> 4;            // node slot 0..15
    int t16    = tid & 15;
    int stream = t16 >> 3;            // 0..1
    int sl     = t16 & 7;
    int b      = (int)blockIdx.x;
    int slab   = (b >= (N_NODES / 16)) ? 1 : 0;
    int v      = (b - slab * (N_NODES / 16)) * 16 + g;
    int col    = slab * 8 + sl;
    int s = node_ptr[v], t = node_ptr[v + 1];
    float s0=0.f,s1=0.f,s2=0.f,s3=0.f,s4=0.f,s5=0.f,s6=0.f,s7=0.f;
    int j = s + stream;
    for (; j + 2 < t; j += 4) {
        int e0 = node_edge[j];
        int e1 = node_edge[j + 2];
        uint4 q0 = m_e[e0 * R16 + col];
        uint4 q1 = m_e[e1 * R16 + col];
        s0 += blo(q0.x) + blo(q1.x); s1 += bhi(q0.x) + bhi(q1.x);
        s2 += blo(q0.y) + blo(q1.y); s3 += bhi(q0.y) + bhi(q1.y);
        s4 += blo(q0.z) + blo(q1.z); s5 += bhi(q0.z) + bhi(q1.z);
        s6 += blo(q0.w) + blo(q1.w); s7 += bhi(q0.w) + bhi(q1.w);
    }
    if (j < t) {
        int e0 = node_edge[j];
        uint4 q0 = m_e[e0 * R16 + col];
        s0 += blo(q0.x); s1 += bhi(q0.x);
        s2 += blo(q0.y); s3 += bhi(q0.y);
        s4 += blo(q0.z); s5 += bhi(q0.z);
        s6 += blo(q0.w); s7 += bhi(q0.w);
    }
    s0 += __shfl_xor(s0, 8); s1 += __shfl_xor(s1, 8);
    s2 += __shfl_xor(s2, 8); s3 += __shfl_xor(s3, 8);
    s4 += __shfl_xor(s4, 8); s5 += __shfl_xor(s5, 8);
    s6 += __shfl_xor(s6, 8); s7 += __shfl_xor(s7, 8);
    if (stream == 0) {
        float dvv = dv_is[v];
        float scf = ca * dvv * dvv;           // 0 for isolated nodes (sum=0 anyway)
        int idx = v * R16 + col;
        uint4 tp = tio[idx];
        float t0 = scf * s0 + cb * blo(tp.x);
        float t1 = scf * s1 + cb * bhi(tp.x);
        float t2 = scf * s2 + cb * blo(tp.y);
        float t3 = scf * s3 + cb * bhi(tp.y);
        float t4 = scf * s4 + cb * blo(tp.z);
        float t5 = scf * s5 + cb * bhi(tp.z);
        float t6 = scf * s6 + cb * blo(tp.w);
        float t7 = scf * s7 + cb * bhi(tp.w);
        uint4 tn;
        tn.x = pack2(t0, t1); tn.y = pack2(t2, t3);
        tn.z = pack2(t4, t5); tn.w = pack2(t6, t7);
        tio[idx] = tn;
        if (accMode) {
            float thk = theta[k];
            float a0 = thk * t0, a1 = thk * t1, a2 = thk * t2, a3 = thk * t3;
            float a4 = thk * t4, a5 = thk * t5, a6 = thk * t6, a7 = thk * t7;
            if (accMode >= 2) {
                float th1 = theta[k - 1];
                uint4 tq = tin[idx];          // V_{k-1}, coalesced
                a0 += th1 * blo(tq.x); a1 += th1 * bhi(tq.x);
                a2 += th1 * blo(tq.y); a3 += th1 * bhi(tq.y);
                a4 += th1 * blo(tq.z); a5 += th1 * bhi(tq.z);
                a6 += th1 * blo(tq.w); a7 += th1 * bhi(tq.w);
            }
            if (accMode >= 3) {
                float th2 = theta[k - 2];
                a0 += th2 * blo(tp.x); a1 += th2 * bhi(tp.x);
                a2 += th2 * blo(tp.y); a3 += th2 * bhi(tp.y);
                a4 += th2 * blo(tp.z); a5 += th2 * bhi(tp.z);
                a6 += th2 * blo(tp.w); a7 += th2 * bhi(tp.w);
            }
            float iw = (dvv > 0.f) ? (1.f / dvv) : 1.f;
            float4* acc4 = (float4*)acc;
            int ai = v * 32 + col * 2;
            float4 a = acc4[ai];
            a.x += iw * a0; a.y += iw * a1; a.z += iw * a2; a.w += iw * a3;
            acc4[ai] = a;
            float4 bvec = acc4[ai + 1];
            bvec.x += iw * a4; bvec.y += iw * a5; bvec.z += iw * a6; bvec.w += iw * a7;
            acc4[ai + 1] = bvec;
        }
    }
}

// ---------------------------------------------------------------- MFMA GEMM
// out = relu(A @ W^T + b), A=accv fp32 [M][128], W fp32 [512][128].
// Block: 256thr=4 waves, tile M=64 N=64, K=128 fully staged.
// LDS row = 136 shorts (272B): conflict-free. XCD swizzle: id&7 = band.
#define M_TILES 782
__global__ __launch_bounds__(256) void k_gemm(const float* __restrict__ A,
                                              const float* __restrict__ W,
                                              const float* __restrict__ bias,
                                              float* __restrict__ out) {
    __shared__ short Asm[64 * 136];
    __shared__ short Wsm[64 * 136];
    int id  = (int)blockIdx.x;
    int xcd = id & 7;
    int sub = id >> 3;
    int h_t = sub & 7;
    int m_i = sub >> 3;                 // 0..97
    int m_t = xcd * 98 + m_i;
    if (m_t >= M_TILES) return;
    int m0 = m_t * 64;
    int h0 = h_t * 64;
    int tid = (int)threadIdx.x;

    const float4* A4 = (const float4*)A;
    const float4* W4 = (const float4*)W;
#pragma unroll
    for (int i = 0; i < 4; ++i) {
        int c   = tid + i * 256;        // 0..1023
        int row = c >> 4;               // 0..63
        int q4  = c & 15;               // uint4 column
        int gr = m0 + row;
        float4 a0, a1;
        if (gr < N_NODES) {
            a0 = A4[(size_t)gr * 32 + q4 * 2];
            a1 = A4[(size_t)gr * 32 + q4 * 2 + 1];
        } else {
            a0 = make_float4(0.f, 0.f, 0.f, 0.f);
            a1 = a0;
        }
        uint4 pa;
        pa.x = pack2(a0.x, a0.y); pa.y = pack2(a0.z, a0.w);
        pa.z = pack2(a1.x, a1.y); pa.w = pack2(a1.z, a1.w);
        *(uint4*)&Asm[row * 136 + q4 * 8] = pa;
        float4 w0 = W4[(size_t)(h0 + row) * 32 + q4 * 2];
        float4 w1 = W4[(size_t)(h0 + row) * 32 + q4 * 2 + 1];
        uint4 pw;
        pw.x = pack2(w0.x, w0.y); pw.y = pack2(w0.z, w0.w);
        pw.z = pack2(w1.x, w1.y); pw.w = pack2(w1.z, w1.w);
        *(uint4*)&Wsm[row * 136 + q4 * 8] = pw;
    }
    __syncthreads();

    int lane = tid & 63;
    int wv   = tid >> 6;                // wave 0..3 -> m rows wv*16..+15
    int l16  = lane & 15;
    int quad = lane >> 4;

    f32x4 acc[4];
#pragma unroll
    for (int n = 0; n < 4; ++n) acc[n] = (f32x4){0.f, 0.f, 0.f, 0.f};

#pragma unroll
    for (int ks = 0; ks < 4; ++ks) {
        int k0 = ks * 32;
        bf16x8 af = *(const bf16x8*)&Asm[(wv * 16 + l16) * 136 + k0 + quad * 8];
#pragma unroll
        for (int n = 0; n < 4; ++n) {
            bf16x8 bf = *(const bf16x8*)&Wsm[(n * 16 + l16) * 136 + k0 + quad * 8];
            acc[n] = __builtin_amdgcn_mfma_f32_16x16x32_bf16(af, bf, acc[n], 0, 0, 0);
        }
    }

    // C/D layout: col = lane&15, row = quad*4 + reg   (m89/m91-verified)
#pragma unroll
    for (int n = 0; n < 4; ++n) {
        float bb = bias[h0 + n * 16 + l16];
#pragma unroll
        for (int r = 0; r < 4; ++r) {
            int gr = m0 + wv * 16 + quad * 4 + r;
            if (gr < N_NODES)
                out[(size_t)gr * HID + h0 + n * 16 + l16] =
                    fmaxf(acc[n][r] + bb, 0.f);
        }
    }
}

// ----------------------------------------------------------------
extern "C" void kernel_launch(void* const* d_in, const int* in_sizes, int n_in,
                              void* d_out, int out_size, void* d_ws, size_t ws_size,
                              hipStream_t stream) {
    const float* x     = (const float*)d_in[0];
    const int*   hidx  = (const int*)d_in[1];    // int32, [2, NNZ] row-major
    const float* ew    = (const float*)d_in[2];
    const float* theta = (const float*)d_in[3];
    const float* w1    = (const float*)d_in[4];
    const float* b1    = (const float*)d_in[5];
    float*       out   = (float*)d_out;
    int kp1 = in_sizes[3];  // K+1 (= 11)
    int K   = kp1 - 1;

    // ---- scratch carved out of d_out (all dead before k_gemm's writes) ----
    char* ob = (char*)d_out;
    size_t oo = 0;
    auto oalloc = [&](size_t bytes) -> void* {
        void* p = ob + oo;
        oo = (oo + bytes + 255) & ~(size_t)255;
        return p;
    };
    uint4* bufA      = (uint4*)oalloc((size_t)N_NODES * F_IN * 2);
    uint4* bufB      = (uint4*)oalloc((size_t)N_NODES * F_IN * 2);
    uint4* m_e       = (uint4*)oalloc((size_t)N_EDGES * F_IN * 2);
    int*   edge_node = (int*)oalloc((size_t)NNZ * 4);
    int*   node_edge = (int*)oalloc((size_t)NNZ * 4);
    unsigned short* loc_e = (unsigned short*)oalloc((size_t)NNZ * 2);
    unsigned short* loc_v = (unsigned short*)oalloc((size_t)NNZ * 2);
    unsigned* hist_e = (unsigned*)oalloc((size_t)HB * NW_E * 4);
    unsigned* hist_n = (unsigned*)oalloc((size_t)HB * NW_N * 4);
    int*   base_e    = (int*)oalloc((size_t)HB * N_EDGES * 4);
    int*   base_n    = (int*)oalloc((size_t)HB * N_NODES * 4);
    int*   counts_e  = (int*)oalloc((size_t)N_EDGES * 4);
    int*   counts_n  = (int*)oalloc((size_t)N_NODES * 4);

    // ---- d_ws (~26MB) ----
    char* ws = (char*)d_ws;
    size_t off = 0;
    auto alloc = [&](size_t bytes) -> void* {
        void* p = ws + off;
        off = (off + bytes + 255) & ~(size_t)255;
        return p;
    };
    float* accv     = (float*)alloc((size_t)N_NODES * F_IN * 4);
    float* dv_is    = (float*)alloc((size_t)N_NODES * 4);
    float* de_w     = (float*)alloc((size_t)N_EDGES * 4);
    int*   edge_ptr = (int*)alloc((size_t)(N_EDGES + 1) * 4);
    int*   node_ptr = (int*)alloc((size_t)(N_NODES + 1) * 4);
    int*   part_e   = (int*)alloc(64 * 4);
    int*   part_n   = (int*)alloc(64 * 4);

    k_hist<<<HB, 1024, 0, stream>>>(hidx, loc_e, loc_v, hist_e, hist_n);
    k_combine<<<(N_NODES + 255) / 256, 256, 0, stream>>>(hist_e, hist_n,
                                                         base_e, base_n,
                                                         counts_e, counts_n);

    k_scan_blk2<<<NB_E + NB_N, 1024, 0, stream>>>(counts_e, counts_n, edge_ptr, node_ptr,
                                                  part_e, part_n);
    k_scan_top2<<<1, 128, 0, stream>>>(part_e, part_n, edge_ptr + N_EDGES, node_ptr + N_NODES);
    k_scan_add2<<<NB_E + NB_N, 1024, 0, stream>>>(edge_ptr, node_ptr, part_e, part_n);

    k_fill<<<(NNZ + 255) / 256, 256, 0, stream>>>(hidx, edge_ptr, node_ptr,
                                                  loc_e, loc_v, base_e, base_n,
                                                  edge_node, node_edge);
    k_norms2<<<(N_NODES + 255) / 256, 256, 0, stream>>>(ew, edge_ptr, node_ptr,
                                                        node_edge, dv_is, de_w);
    k_init<<<(N_NODES * R16 + 255) / 256, 256, 0, stream>>>(x, theta, dv_is, bufA, accv);

    for (int k = 1; k <= K; ++k) {
        const uint4* tin = (k & 1) ? bufA : bufB;   // V_{k-1}
        uint4*       tio = (k & 1) ? bufB : bufA;   // V_{k-2} -> V_k (in place)
        float ca = (k == 1) ? -1.f : -2.f;
        float cb = (k == 1) ? 0.f : -1.f;
        int accMode = 0;
        if (k % 3 == 0) accMode = 3;
        else if (k == K && (K % 3) != 0) accMode = K % 3;
        // 2 slabs x 2500 edge-blocks; 2 slabs x 3125 node-blocks
        k_phaseA<<<2 * (N_EDGES / 4), 256, 0, stream>>>(tin, de_w, edge_ptr, edge_node, m_e);
        k_phaseB<<<2 * (N_NODES / 16), 256, 0, stream>>>(m_e, tin, dv_is, node_ptr, node_edge,
                                                         tio, accv, theta, k, ca, cb, accMode);
    }

    // 8 bands x 98 m-tiles x 8 h-tiles (2 tail tiles early-return)
    k_gemm<<<8 * 98 * 8, 256, 0, stream>>>(accv, w1, b1, out);
}